// Round 15
// baseline (93.722 us; speedup 1.0000x reference)
//
#include <hip/hip_runtime.h>
#include <math.h>

// Soft silhouette renderer — coarse tile gate + wave-split render (R15).
// verts: (4, 778, 3) f32   faces: (1538, 3) i32   out: (4, 320, 320) f32
//
// Verified-exact math core (R4, absmax 0.0):
//   area2 = fma(dx1, dy2, -round(dy1*dx2)) — matches the reference
//   evaluator's contraction; degenerate faces (sgn=0 -> 1/8 veil, i1==i2
//   sliver -> sigma=1/2 ridge) fall out of the generic edge code.
//
// R14 post-mortem: 8-wave split neutral — aggregate-bound. Hidden tax:
// staging re-reads 1538 faces x 48 B x 6400 blocks = 470 MB of L2 (~14 us
// at 34.5 TB/s), paid even by tiles with zero silhouette math.
// This round: COARSE (32x32 px) PRE-PASS, 100 ctiles/image:
//  * nCov = faces with m_lo(coarse) > T: each covers every pixel with all
//    x>=12 => sigma-product > 1-1e-6 => ref clips prob=1-1e-6 => factor
//    EXACTLY 1e-6. nCov>=2 => tot<=1e-12 => ref's 1-exp rounds to 1.0f.
//    Gate writes 1.0f — bit-identical to the full computation.
//  * nCov==0 && nBand==0 => fine cull (smaller reach) also finds nothing
//    => R14 would output exactly 0.0f. Gate writes 0.0f — bit-identical.
//  * everything else: unchanged R14 path (512 thr, 2 chunks, cover fold,
//    index compaction, scalar j-loop, live gates).
// Render L2 staging drops ~470 -> ~200 MB; dead blocks cost ~40 cycles.
//
// Error budget vs 2e-2 (measured 0.00390625 = bf16 harness floor since R5):
// gates add ZERO new error (bit-equivalent); cull skip <= 1538*e^-12 =
// 9.4e-3 worst-case; covering shortcut <=1.5e-6/face; saturation cut
// 2.3e-6; product rounding ~1e-4.

#define IMG_S 320
#define N_FACES 1538
#define N_VERTS 778
#define N_BATCH 4
#define FP 1600            // padded face stride in ws
#define TILE 8
#define BLOCK 512
#define CHUNK_F 768        // faces per chunk (2 chunks: 768 + 770)
#define NWAVE 8
#define CT_PS 10           // coarse tiles per side (32x32 px each)
#define INV_SIGMA 100.0f
#define T_CUT 12.0f
#define ACC_CUT_P 2.2603294e-6f    // e^-13, product-domain saturation
#define LOG2_1EM6 -19.9315686f     // log2(1e-6)

__global__ __launch_bounds__(256)
void prep_faces(const float* __restrict__ verts,
                const int* __restrict__ faces,
                float4* __restrict__ gE0,
                float4* __restrict__ gE1,
                float4* __restrict__ gE2)
{
    const int f = blockIdx.x * 256 + threadIdx.x;
    const int b = blockIdx.z;
    if (f >= N_FACES) return;

    const float* vb = verts + (size_t)b * N_VERTS * 3;
    const int i0 = faces[f * 3 + 0];
    const int i1 = faces[f * 3 + 1];
    const int i2 = faces[f * 3 + 2];
    const float x0 = vb[i0 * 3 + 0], y0 = -vb[i0 * 3 + 1];
    const float x1 = vb[i1 * 3 + 0], y1 = -vb[i1 * 3 + 1];
    const float x2 = vb[i2 * 3 + 0], y2 = -vb[i2 * 3 + 1];

    // VERIFIED-EXACT (R4): fma-contracted area2 — do not change.
    const float dx1 = x1 - x0, dy1 = y1 - y0;
    const float dx2 = x2 - x0, dy2 = y2 - y0;
    const float area2 = __builtin_fmaf(dx1, dy2, -__fmul_rn(dy1, dx2));
    const float sgn = (area2 > 0.0f) ? 1.0f : ((area2 < 0.0f) ? -1.0f : 0.0f);

    const size_t o = (size_t)b * FP + f;
    {   // edge v0 -> v1
        const float ex = x1 - x0, ey = y1 - y0;
        const float s = sgn * INV_SIGMA / (sqrtf(ex * ex + ey * ey) + 1e-8f);
        gE0[o] = make_float4(-s * ey, s * ex, s * (ey * x0 - ex * y0), 0.0f);
    }
    {   // edge v1 -> v2
        const float ex = x2 - x1, ey = y2 - y1;
        const float s = sgn * INV_SIGMA / (sqrtf(ex * ex + ey * ey) + 1e-8f);
        gE1[o] = make_float4(-s * ey, s * ex, s * (ey * x1 - ex * y1), 0.0f);
    }
    {   // edge v2 -> v0
        const float ex = x0 - x2, ey = y0 - y2;
        const float s = sgn * INV_SIGMA / (sqrtf(ex * ex + ey * ey) + 1e-8f);
        gE2[o] = make_float4(-s * ey, s * ex, s * (ey * x2 - ex * y2), 0.0f);
    }
}

// Coarse classify: per (batch, 32x32-px coarse tile), count covering and
// band faces. 400 blocks x 1538 faces = 30 MB L2, ~1-2 us.
__global__ __launch_bounds__(256)
void prep_coarse(const float4* __restrict__ gE0,
                 const float4* __restrict__ gE1,
                 const float4* __restrict__ gE2,
                 int* __restrict__ gCov,
                 int* __restrict__ gBand)
{
    __shared__ int lCov, lBand;
    const int t  = threadIdx.x;
    const int ct = blockIdx.x;        // coarse tile id 0..99
    const int b  = blockIdx.z;
    if (t == 0) { lCov = 0; lBand = 0; }
    __syncthreads();

    const float w  = 2.0f / IMG_S;
    const float cx = ((ct % CT_PS) * 32 + 16) * w - 1.0f;
    const float cy = ((ct / CT_PS) * 32 + 16) * w - 1.0f;
    const float rr = 15.5f * w;       // half-extent of 32x32 pixel centers

    const float4* gb0 = gE0 + (size_t)b * FP;
    const float4* gb1 = gE1 + (size_t)b * FP;
    const float4* gb2 = gE2 + (size_t)b * FP;

    int nc = 0, nb = 0;
    for (int f = t; f < N_FACES; f += 256) {
        const float4 e0 = gb0[f];
        const float4 e1 = gb1[f];
        const float4 e2 = gb2[f];
        const float c0 = fmaf(e0.x, cx, fmaf(e0.y, cy, e0.z));
        const float c1 = fmaf(e1.x, cx, fmaf(e1.y, cy, e1.z));
        const float c2 = fmaf(e2.x, cx, fmaf(e2.y, cy, e2.z));
        const float r0 = rr * (fabsf(e0.x) + fabsf(e0.y));
        const float r1 = rr * (fabsf(e1.x) + fabsf(e1.y));
        const float r2 = rr * (fabsf(e2.x) + fabsf(e2.y));
        const float m_hi = fminf(c0 + r0, fminf(c1 + r1, c2 + r2));
        const float m_lo = fminf(c0 - r0, fminf(c1 - r1, c2 - r2));
        if (m_lo > T_CUT) nc++;
        else if (m_hi > -T_CUT) nb++;
    }
    atomicAdd(&lCov, nc);
    atomicAdd(&lBand, nb);
    __syncthreads();
    if (t == 0) {
        gCov[b * (CT_PS * CT_PS) + ct]  = lCov;
        gBand[b * (CT_PS * CT_PS) + ct] = lBand;
    }
}

__global__ __launch_bounds__(BLOCK)
void silhouette_ws(const float4* __restrict__ gE0,
                   const float4* __restrict__ gE1,
                   const float4* __restrict__ gE2,
                   const int* __restrict__ gCov,
                   const int* __restrict__ gBand,
                   float* __restrict__ out)
{
    __shared__ int sIdx[CHUNK_F + 8];
    __shared__ float sAcc[BLOCK];
    __shared__ int sCount;
    __shared__ int sAlive;
    __shared__ int sCover;

    const int t    = threadIdx.x;
    const int wave = t >> 6;
    const int lane = t & 63;
    const int p    = t & 63;          // pixel id within 8x8 tile
    const int plx  = p & 7;
    const int ply  = p >> 3;
    const int b    = blockIdx.z;
    const int gx   = blockIdx.x * TILE + plx;
    const int gy   = blockIdx.y * TILE + ply;

    // ---- coarse gate: bit-equivalent early outs ----
    const int ct   = (blockIdx.y >> 2) * CT_PS + (blockIdx.x >> 2);
    const int nCov = gCov[b * (CT_PS * CT_PS) + ct];
    {
        const int nBnd = gBand[b * (CT_PS * CT_PS) + ct];
        if (nCov >= 2) {
            if (t < 64)
                out[(size_t)b * (IMG_S * IMG_S) + (size_t)gy * IMG_S + gx] = 1.0f;
            return;
        }
        if (nCov == 0 && nBnd == 0) {
            if (t < 64)
                out[(size_t)b * (IMG_S * IMG_S) + (size_t)gy * IMG_S + gx] = 0.0f;
            return;
        }
    }

    const float w  = 2.0f / IMG_S;
    const float px = (gx + 0.5f) * w - 1.0f;
    const float py = (gy + 0.5f) * w - 1.0f;
    const float cx = (blockIdx.x * TILE + 4) * w - 1.0f;
    const float cy = (blockIdx.y * TILE + 4) * w - 1.0f;
    const float rr = 3.5f * w;

    const float4* gb0 = gE0 + (size_t)b * FP;   // per-batch base
    const float4* gb1 = gE1 + (size_t)b * FP;
    const float4* gb2 = gE2 + (size_t)b * FP;

    float acc = 1.0f;   // product of (1-prob) over this wave's face subset
                        // (wave 0 also carries the cover factors)

    for (int c = 0; c < 2; ++c) {
        const int base = c * CHUNK_F;
        const int end  = (c == 0) ? CHUNK_F : N_FACES;

        sAcc[t] = acc;
        if (t == 0) { sCount = 0; sAlive = 0; sCover = 0; }
        __syncthreads();   // B1: resets + partials visible

        float tot = sAcc[p];
        #pragma unroll
        for (int k = 1; k < NWAVE; ++k) tot *= sAcc[p + 64 * k];
        const bool alive = (tot > ACC_CUT_P);
        if (alive) sAlive = 1;               // benign same-value race
        __syncthreads();   // B2: vote final — break BEFORE staging

        if (sAlive == 0) break;   // uniform: every pixel saturated

        // ---- staging: classify faces, compact band INDICES ----
        for (int fb = base; fb < end; fb += BLOCK) {
            const int fc = fb + t;
            const bool vald = (fc < end);
            const int fcc = vald ? fc : (end - 1);
            const float4 e0 = gb0[fcc];      // coalesced vector loads
            const float4 e1 = gb1[fcc];
            const float4 e2 = gb2[fcc];
            const float c0 = fmaf(e0.x, cx, fmaf(e0.y, cy, e0.z));
            const float c1 = fmaf(e1.x, cx, fmaf(e1.y, cy, e1.z));
            const float c2 = fmaf(e2.x, cx, fmaf(e2.y, cy, e2.z));
            const float r0 = rr * (fabsf(e0.x) + fabsf(e0.y));
            const float r1 = rr * (fabsf(e1.x) + fabsf(e1.y));
            const float r2 = rr * (fabsf(e2.x) + fabsf(e2.y));
            const float m_hi = fminf(c0 + r0, fminf(c1 + r1, c2 + r2));
            const float m_lo = fminf(c0 - r0, fminf(c1 - r1, c2 - r2));
            const bool isCov  = vald && (m_lo > T_CUT);
            const bool isBand = vald && !isCov && (m_hi > -T_CUT);

            const unsigned long long mb = __ballot(isBand);
            int wbase = 0;
            if (lane == 0) {
                const int nw = __popcll(mb);
                if (nw) wbase = atomicAdd(&sCount, nw);
            }
            wbase = __shfl(wbase, 0);
            if (isBand) {
                sIdx[wbase + __popcll(mb & ((1ull << lane) - 1ull))] = fc;
            }
            const unsigned long long mc = __ballot(isCov);
            if (lane == 0) {
                const int ncv = __popcll(mc);
                if (ncv) atomicAdd(&sCover, ncv);
            }
        }
        __syncthreads();   // B3: compaction + cover count final

        const float coverF = exp2f((float)sCover * LOG2_1EM6);
        bool live = alive && (acc * coverF > ACC_CUT_P);
        if (wave == 0) acc *= coverF;

        const int n = sCount;
        int j = wave;
        while (j < n) {
            if (__ballot(live) == 0ull) break;   // whole wave saturated
            const int jstop = j + 4 * NWAVE;     // 4 iters per ballot
            for (; j < n && j < jstop; j += NWAVE) {
                int fj = sIdx[j];                // 4B broadcast read
                fj = __builtin_amdgcn_readfirstlane(fj);
                const float4 e0 = gb0[fj];       // wave-uniform scalar loads
                const float4 e1 = gb1[fj];
                const float4 e2 = gb2[fj];
                const float xa = fmaf(e0.x, px, fmaf(e0.y, py, e0.z));
                const float xb = fmaf(e1.x, px, fmaf(e1.y, py, e1.z));
                const float xc = fmaf(e2.x, px, fmaf(e2.y, py, e2.z));
                const float m = fminf(xa, fminf(xb, xc));
                if (live && m > -T_CUT) {
                    float f;
                    if (m > T_CUT) {
                        f = 1e-6f;   // pixel-covering: ref clips at 1-1e-6
                    } else {
                        const float mid = fmaxf(fminf(fmaxf(xa, xb), xc),
                                                fminf(xa, xb));   // median
                        if (mid > T_CUT) {
                            // single edge in band: f = sigma(-m) >= 6e-6
                            f = 1.0f - __builtin_amdgcn_rcpf(1.0f + __expf(-m));
                        } else {
                            const float da = 1.0f + __expf(-xa);
                            const float db = 1.0f + __expf(-xb);
                            const float dc = 1.0f + __expf(-xc);
                            f = 1.0f - __builtin_amdgcn_rcpf(da * db * dc);
                        }
                    }
                    acc *= f;
                    live = (acc > ACC_CUT_P);
                }
            }
        }

        __syncthreads();   // B4: j-loop index reads done before next chunk
    }

    // final reduction + output (loop exits are block-uniform)
    sAcc[t] = acc;
    __syncthreads();
    if (t < 64) {
        float tot = sAcc[p];
        #pragma unroll
        for (int k = 1; k < NWAVE; ++k) tot *= sAcc[p + 64 * k];
        out[(size_t)b * (IMG_S * IMG_S) + (size_t)gy * IMG_S + gx] = 1.0f - tot;
    }
}

extern "C" void kernel_launch(void* const* d_in, const int* in_sizes, int n_in,
                              void* d_out, int out_size, void* d_ws, size_t ws_size,
                              hipStream_t stream) {
    const float* verts = (const float*)d_in[0];
    const int* faces = (const int*)d_in[1];
    float* out = (float*)d_out;

    // ws layout: 3 arrays of float4[N_BATCH * FP] (307 KB) + coarse counts
    float4* gE0 = (float4*)d_ws;
    float4* gE1 = gE0 + (size_t)N_BATCH * FP;
    float4* gE2 = gE1 + (size_t)N_BATCH * FP;
    int* gCov  = (int*)(gE2 + (size_t)N_BATCH * FP);
    int* gBand = gCov + N_BATCH * CT_PS * CT_PS;

    dim3 pgrid((N_FACES + 255) / 256, 1, N_BATCH);
    prep_faces<<<pgrid, 256, 0, stream>>>(verts, faces, gE0, gE1, gE2);

    dim3 cgrid(CT_PS * CT_PS, 1, N_BATCH);
    prep_coarse<<<cgrid, 256, 0, stream>>>(gE0, gE1, gE2, gCov, gBand);

    dim3 grid(IMG_S / TILE, IMG_S / TILE, N_BATCH);
    silhouette_ws<<<grid, BLOCK, 0, stream>>>(gE0, gE1, gE2, gCov, gBand, out);
}

// Round 16
// 88.157 us; speedup vs baseline: 1.0631x; 1.0631x over previous
//
#include <hip/hip_runtime.h>
#include <math.h>

// Soft silhouette renderer — R16 = R13 (measured best, bench 88.0 us)
// minus the provably-dead fmaxf floor.
// verts: (4, 778, 3) f32   faces: (1538, 3) i32   out: (4, 320, 320) f32
//
// Verified-exact math core (R4, absmax 0.0):
//   area2 = fma(dx1, dy2, -round(dy1*dx2)) — matches the reference
//   evaluator's contraction; degenerate faces (sgn=0 -> 1/8 veil, i1==i2
//   sliver -> sigma=1/2 ridge) fall out of the generic edge code.
//
// R14/R15 post-mortem: 8-wave block (-2.5us), grouped ballot (neutral),
// coarse-gate 3rd launch (-3us) were all net-negative vs R13; the harness's
// own 268MB ws-poison fill (~40us @ 84% HBM peak) is the uncontrollable
// ~50us bench floor. This round reverts to the R13 configuration exactly:
//  * 256-thread blocks, 4-wave face split, static 6400-block grid
//  * 2 chunks (768/770), alive-vote BEFORE staging
//  * index-only LDS compaction (ballot-scan, 1 atomic/wave)
//  * j-loop: per-iter ballot-break, wave-uniform scalar face loads
// Only delta vs R13: dropped fmaxf(f,1e-6) — inactive for m<=T_CUT=12
// (1-prob >= 6e-6 in both band paths).
//
// Error budget vs 2e-2 tolerance (measured 0.00390625 = one bf16 ulp =
// harness quantization floor since R5): cull skip <= 1538*e^-12 = 9.4e-3
// worst-case; covering shortcut <=1.5e-6/face; saturation cut e^-13 ->
// 2.3e-6; product rounding ~1e-4.

#define IMG_S 320
#define N_FACES 1538
#define N_VERTS 778
#define N_BATCH 4
#define FP 1600            // padded face stride in ws
#define TILE 8
#define CHUNK_F 768        // faces per chunk (2 chunks: 768 + 770)
#define NWAVE 4
#define INV_SIGMA 100.0f
#define T_CUT 12.0f
#define ACC_CUT_P 2.2603294e-6f    // e^-13, product-domain saturation
#define LOG2_1EM6 -19.9315686f     // log2(1e-6)

__global__ __launch_bounds__(256)
void prep_faces(const float* __restrict__ verts,
                const int* __restrict__ faces,
                float4* __restrict__ gE0,
                float4* __restrict__ gE1,
                float4* __restrict__ gE2)
{
    const int f = blockIdx.x * 256 + threadIdx.x;
    const int b = blockIdx.z;
    if (f >= N_FACES) return;

    const float* vb = verts + (size_t)b * N_VERTS * 3;
    const int i0 = faces[f * 3 + 0];
    const int i1 = faces[f * 3 + 1];
    const int i2 = faces[f * 3 + 2];
    const float x0 = vb[i0 * 3 + 0], y0 = -vb[i0 * 3 + 1];
    const float x1 = vb[i1 * 3 + 0], y1 = -vb[i1 * 3 + 1];
    const float x2 = vb[i2 * 3 + 0], y2 = -vb[i2 * 3 + 1];

    // VERIFIED-EXACT (R4): fma-contracted area2 — do not change.
    const float dx1 = x1 - x0, dy1 = y1 - y0;
    const float dx2 = x2 - x0, dy2 = y2 - y0;
    const float area2 = __builtin_fmaf(dx1, dy2, -__fmul_rn(dy1, dx2));
    const float sgn = (area2 > 0.0f) ? 1.0f : ((area2 < 0.0f) ? -1.0f : 0.0f);

    const size_t o = (size_t)b * FP + f;
    {   // edge v0 -> v1
        const float ex = x1 - x0, ey = y1 - y0;
        const float s = sgn * INV_SIGMA / (sqrtf(ex * ex + ey * ey) + 1e-8f);
        gE0[o] = make_float4(-s * ey, s * ex, s * (ey * x0 - ex * y0), 0.0f);
    }
    {   // edge v1 -> v2
        const float ex = x2 - x1, ey = y2 - y1;
        const float s = sgn * INV_SIGMA / (sqrtf(ex * ex + ey * ey) + 1e-8f);
        gE1[o] = make_float4(-s * ey, s * ex, s * (ey * x1 - ex * y1), 0.0f);
    }
    {   // edge v2 -> v0
        const float ex = x0 - x2, ey = y0 - y2;
        const float s = sgn * INV_SIGMA / (sqrtf(ex * ex + ey * ey) + 1e-8f);
        gE2[o] = make_float4(-s * ey, s * ex, s * (ey * x2 - ex * y2), 0.0f);
    }
}

__global__ __launch_bounds__(256)
void silhouette_ws(const float4* __restrict__ gE0,
                   const float4* __restrict__ gE1,
                   const float4* __restrict__ gE2,
                   float* __restrict__ out)
{
    __shared__ int sIdx[CHUNK_F + 8];
    __shared__ float sAcc[256];
    __shared__ int sCount;
    __shared__ int sAlive;
    __shared__ int sCover;

    const int t    = threadIdx.x;
    const int wave = t >> 6;
    const int lane = t & 63;
    const int p    = t & 63;          // pixel id within 8x8 tile
    const int plx  = p & 7;
    const int ply  = p >> 3;
    const int b    = blockIdx.z;
    const int gx   = blockIdx.x * TILE + plx;
    const int gy   = blockIdx.y * TILE + ply;

    const float w  = 2.0f / IMG_S;
    const float px = (gx + 0.5f) * w - 1.0f;
    const float py = (gy + 0.5f) * w - 1.0f;
    const float cx = (blockIdx.x * TILE + 4) * w - 1.0f;
    const float cy = (blockIdx.y * TILE + 4) * w - 1.0f;
    const float rr = 3.5f * w;

    const float4* gb0 = gE0 + (size_t)b * FP;   // per-batch base
    const float4* gb1 = gE1 + (size_t)b * FP;
    const float4* gb2 = gE2 + (size_t)b * FP;

    float acc = 1.0f;   // product of (1-prob) over this wave's face subset
                        // (wave 0 also carries the cover factors)

    for (int c = 0; c < 2; ++c) {
        const int base = c * CHUNK_F;
        const int end  = (c == 0) ? CHUNK_F : N_FACES;

        sAcc[t] = acc;
        if (t == 0) { sCount = 0; sAlive = 0; sCover = 0; }
        __syncthreads();   // B1: resets + partials visible

        const float tot = sAcc[p] * sAcc[p + 64] * sAcc[p + 128] * sAcc[p + 192];
        const bool alive = (tot > ACC_CUT_P);
        if (alive) sAlive = 1;               // benign same-value race
        __syncthreads();   // B2: vote final — break BEFORE staging

        if (sAlive == 0) break;   // uniform: every pixel saturated

        // ---- staging: classify faces, compact band INDICES ----
        for (int fb = base; fb < end; fb += 256) {
            const int fc = fb + t;
            const bool vald = (fc < end);
            const int fcc = vald ? fc : (end - 1);
            const float4 e0 = gb0[fcc];      // coalesced vector loads
            const float4 e1 = gb1[fcc];
            const float4 e2 = gb2[fcc];
            const float c0 = fmaf(e0.x, cx, fmaf(e0.y, cy, e0.z));
            const float c1 = fmaf(e1.x, cx, fmaf(e1.y, cy, e1.z));
            const float c2 = fmaf(e2.x, cx, fmaf(e2.y, cy, e2.z));
            const float r0 = rr * (fabsf(e0.x) + fabsf(e0.y));
            const float r1 = rr * (fabsf(e1.x) + fabsf(e1.y));
            const float r2 = rr * (fabsf(e2.x) + fabsf(e2.y));
            const float m_hi = fminf(c0 + r0, fminf(c1 + r1, c2 + r2));
            const float m_lo = fminf(c0 - r0, fminf(c1 - r1, c2 - r2));
            const bool isCov  = vald && (m_lo > T_CUT);
            const bool isBand = vald && !isCov && (m_hi > -T_CUT);

            const unsigned long long mb = __ballot(isBand);
            int wbase = 0;
            if (lane == 0) {
                const int nw = __popcll(mb);
                if (nw) wbase = atomicAdd(&sCount, nw);
            }
            wbase = __shfl(wbase, 0);
            if (isBand) {
                sIdx[wbase + __popcll(mb & ((1ull << lane) - 1ull))] = fc;
            }
            const unsigned long long mc = __ballot(isCov);
            if (lane == 0) {
                const int ncv = __popcll(mc);
                if (ncv) atomicAdd(&sCover, ncv);
            }
        }
        __syncthreads();   // B3: compaction + cover count final

        const float coverF = exp2f((float)sCover * LOG2_1EM6);
        bool live = alive && (acc * coverF > ACC_CUT_P);
        if (wave == 0) acc *= coverF;

        const int n = sCount;
        for (int j = wave; j < n; j += NWAVE) {
            if (__ballot(live) == 0ull) break;   // whole wave saturated
            int fj = sIdx[j];                    // 4B broadcast read
            fj = __builtin_amdgcn_readfirstlane(fj);
            const float4 e0 = gb0[fj];           // wave-uniform scalar loads
            const float4 e1 = gb1[fj];
            const float4 e2 = gb2[fj];
            const float xa = fmaf(e0.x, px, fmaf(e0.y, py, e0.z));
            const float xb = fmaf(e1.x, px, fmaf(e1.y, py, e1.z));
            const float xc = fmaf(e2.x, px, fmaf(e2.y, py, e2.z));
            const float m = fminf(xa, fminf(xb, xc));
            if (live && m > -T_CUT) {
                float f;
                if (m > T_CUT) {
                    f = 1e-6f;   // pixel-covering: ref clips prob at 1-1e-6
                } else {
                    const float mid = fmaxf(fminf(fmaxf(xa, xb), xc),
                                            fminf(xa, xb));   // median
                    if (mid > T_CUT) {
                        // single edge in band: f = sigma(-m) >= 6e-6
                        f = 1.0f - __builtin_amdgcn_rcpf(1.0f + __expf(-m));
                    } else {
                        const float da = 1.0f + __expf(-xa);
                        const float db = 1.0f + __expf(-xb);
                        const float dc = 1.0f + __expf(-xc);
                        f = 1.0f - __builtin_amdgcn_rcpf(da * db * dc);
                    }
                }
                acc *= f;
                live = (acc > ACC_CUT_P);
            }
        }

        __syncthreads();   // B4: j-loop index reads done before next chunk
    }

    // final reduction + output (loop exits are block-uniform)
    sAcc[t] = acc;
    __syncthreads();
    if (t < 64) {
        const float tot = sAcc[p] * sAcc[p + 64] * sAcc[p + 128] * sAcc[p + 192];
        out[(size_t)b * (IMG_S * IMG_S) + (size_t)gy * IMG_S + gx] = 1.0f - tot;
    }
}

extern "C" void kernel_launch(void* const* d_in, const int* in_sizes, int n_in,
                              void* d_out, int out_size, void* d_ws, size_t ws_size,
                              hipStream_t stream) {
    const float* verts = (const float*)d_in[0];
    const int* faces = (const int*)d_in[1];
    float* out = (float*)d_out;

    // ws layout: 3 arrays of float4[N_BATCH * FP]  (3 * 4*1600*16B = 307 KB)
    float4* gE0 = (float4*)d_ws;
    float4* gE1 = gE0 + (size_t)N_BATCH * FP;
    float4* gE2 = gE1 + (size_t)N_BATCH * FP;

    dim3 pgrid((N_FACES + 255) / 256, 1, N_BATCH);
    prep_faces<<<pgrid, 256, 0, stream>>>(verts, faces, gE0, gE1, gE2);

    dim3 grid(IMG_S / TILE, IMG_S / TILE, N_BATCH);
    silhouette_ws<<<grid, 256, 0, stream>>>(gE0, gE1, gE2, out);
}